// Round 3
// baseline (903.434 us; speedup 1.0000x reference)
//
#include <hip/hip_runtime.h>
#include <hip/hip_bf16.h>
#include <cstdint>
#include <cstddef>

// Problem constants
#define S_LEN   2048
#define BATCH   2
#define HDIM    4096
#define NHEADS  32
#define NGROUPS 8
#define HEADD   128
#define QKV_N   6144   // HDIM + 2*NGROUPS*HEADD

typedef __attribute__((ext_vector_type(8))) short  short8;   // 8 bf16 = 4 VGPRs
typedef __attribute__((ext_vector_type(4))) float  floatx4;  // MFMA 16x16 accum

__device__ __forceinline__ void async_ld16(const void* g, void* l) {
  __builtin_amdgcn_global_load_lds((const __attribute__((address_space(1))) void*)g,
                                   (__attribute__((address_space(3))) void*)l,
                                   16, 0, 0);
}

// RTNE f32 -> bf16 bits (finite inputs)
__device__ __forceinline__ unsigned short f2bf_bits(float f) {
  unsigned int u = __float_as_uint(f);
  u += 0x7FFFu + ((u >> 16) & 1u);
  return (unsigned short)(u >> 16);
}

// ---------------------------------------------------------------------------
// f32 -> bf16 bulk convert
// ---------------------------------------------------------------------------
__global__ void cvt_f32_bf16(const float4* __restrict__ in,
                             ushort4* __restrict__ out, int n4)
{
  const int i = blockIdx.x * blockDim.x + threadIdx.x;
  if (i >= n4) return;
  const float4 v = in[i];
  ushort4 o;
  o.x = f2bf_bits(v.x); o.y = f2bf_bits(v.y);
  o.z = f2bf_bits(v.z); o.w = f2bf_bits(v.w);
  out[i] = o;
}

// ---------------------------------------------------------------------------
// GEMM: C[M,N] = A[M,K] @ B[N,K]^T  (bf16, K contiguous), 128x128 tile, BK=64.
// Verified round-0 structure: 3 blocks/CU; cross-block wave overlap fills the
// barrier-drain stall. LDS tiles XOR-swizzled at stage time via the DMA's
// global-side gather (conflict-free fragment reads).
// MODE 0: f32 row-major output. MODE 1: QKV scatter epilogue (+bias f32).
// ---------------------------------------------------------------------------
template<int MODE>
__global__ void gemm128(const __hip_bfloat16* __restrict__ A,
                        const __hip_bfloat16* __restrict__ Bm,
                        const float* __restrict__ bias,
                        float* __restrict__ Cout,
                        __hip_bfloat16* __restrict__ Qbuf,
                        __hip_bfloat16* __restrict__ Kbuf,
                        __hip_bfloat16* __restrict__ Vtbuf,
                        int M, int N, int K)
{
  __shared__ short As[128*64];   // 16 KB, 8 chunks(16B) per row
  __shared__ short Bs[128*64];   // 16 KB
  const int mb = blockIdx.y, nb = blockIdx.x;
  const int tid  = threadIdx.x;
  const int wave = tid >> 6, lane = tid & 63;
  const int wm = wave >> 1, wn = wave & 1;
  const int quad = lane >> 4, l15 = lane & 15;

  floatx4 acc[4][4] = {};

  const __hip_bfloat16* Abase = A  + (size_t)mb * 128 * K;
  const __hip_bfloat16* Bbase = Bm + (size_t)nb * 128 * K;

  for (int kb = 0; kb < K; kb += 64) {
    #pragma unroll
    for (int i = 0; i < 4; ++i) {
      const int cb  = (i*4 + wave) * 64;     // wave-uniform chunk base
      const int idx = cb + lane;
      const int r   = idx >> 3, cl = idx & 7;
      const int gc  = cl ^ (r & 7);          // XOR swizzle (global side)
      async_ld16(Abase + (size_t)r*K + kb + gc*8, As + cb*8);
      async_ld16(Bbase + (size_t)r*K + kb + gc*8, Bs + cb*8);
    }
    __syncthreads();

    #pragma unroll
    for (int ks = 0; ks < 2; ++ks) {
      short8 af[4], bf[4];
      #pragma unroll
      for (int mi = 0; mi < 4; ++mi) {
        const int row = wm*64 + mi*16 + l15;
        const int ch  = (ks*4 + quad) ^ (l15 & 7);
        af[mi] = *(const short8*)&As[row*64 + ch*8];
      }
      #pragma unroll
      for (int ni = 0; ni < 4; ++ni) {
        const int row = wn*64 + ni*16 + l15;
        const int ch  = (ks*4 + quad) ^ (l15 & 7);
        bf[ni] = *(const short8*)&Bs[row*64 + ch*8];
      }
      #pragma unroll
      for (int mi = 0; mi < 4; ++mi)
        #pragma unroll
        for (int ni = 0; ni < 4; ++ni)
          acc[mi][ni] = __builtin_amdgcn_mfma_f32_16x16x32_bf16(
              af[mi], bf[ni], acc[mi][ni], 0, 0, 0);
    }
    __syncthreads();
  }

  // epilogue: C/D layout col = lane&15, row = quad*4 + reg
  #pragma unroll
  for (int mi = 0; mi < 4; ++mi) {
    #pragma unroll
    for (int ni = 0; ni < 4; ++ni) {
      const int n = nb*128 + wn*64 + ni*16 + l15;
      float bv = 0.0f;
      if (MODE == 1) bv = bias[n];
      #pragma unroll
      for (int r = 0; r < 4; ++r) {
        const int m = mb*128 + wm*64 + mi*16 + quad*4 + r;
        const float v = acc[mi][ni][r] + bv;
        if (MODE == 0) {
          Cout[(size_t)m*N + n] = v;
        } else {
          const __hip_bfloat16 hv = __float2bfloat16(v);
          const int s  = m >> 1;       // BATCH = 2
          const int bi = m & 1;
          if (n < HDIM) {                     // Q -> (b,h,s,d)
            const int hh = n >> 7, d = n & 127;
            Qbuf[(((size_t)bi*NHEADS + hh)*S_LEN + s)*HEADD + d] = hv;
          } else if (n < HDIM + NGROUPS*HEADD) {  // K -> (b,g,s,d)
            const int gg = (n - HDIM) >> 7, d = n & 127;
            Kbuf[(((size_t)bi*NGROUPS + gg)*S_LEN + s)*HEADD + d] = hv;
          } else {                            // V -> (b,g,d,s) transposed
            const int gg = (n - (HDIM + NGROUPS*HEADD)) >> 7, d = n & 127;
            Vtbuf[(((size_t)bi*NGROUPS + gg)*HEADD + d)*S_LEN + s] = hv;
          }
        }
      }
    }
  }
}

// ---------------------------------------------------------------------------
// RoPE in-place. Q additionally pre-scaled by 1/sqrt(HD)*log2(e) so attention
// scores come out ready for exp2 (no-max softmax). rope_cache: (S,64,2) f32
// ---------------------------------------------------------------------------
__global__ void rope_kernel(__hip_bfloat16* __restrict__ Qbuf,
                            __hip_bfloat16* __restrict__ Kbuf,
                            const float* __restrict__ rope)
{
  const int QP = BATCH*NHEADS*S_LEN*64;
  const int KP = BATCH*NGROUPS*S_LEN*64;
  int idx = blockIdx.x * blockDim.x + threadIdx.x;
  __hip_bfloat16* base;
  int p;
  float post;
  if (idx < QP)            { base = Qbuf; p = idx;      post = 0.12751744061558475f; }
  else if (idx < QP + KP)  { base = Kbuf; p = idx - QP; post = 1.0f; }
  else return;
  const int i    = p & 63;
  const int rest = p >> 6;
  const int s    = rest & (S_LEN - 1);
  const float c  = rope[s*128 + 2*i];
  const float sn = rope[s*128 + 2*i + 1];
  __hip_bfloat16* ptr = base + (size_t)rest*HEADD + 2*i;
  const float x0 = __bfloat162float(ptr[0]);
  const float x1 = __bfloat162float(ptr[1]);
  ptr[0] = __float2bfloat16((x0*c - x1*sn) * post);
  ptr[1] = __float2bfloat16((x1*c + x0*sn) * post);
}

// ---------------------------------------------------------------------------
// Flash attention v5 (round 3): causal, GQA rep=4.
// ROUND-2 POST-MORTEM: attn is LDS-THROUGHPUT bound, not latency bound
// (per block-iter at 16 q-rows/wave: ~2016 LDS-pipe cy vs 640 MFMA cy —
// every K/V fragment ds_read fed exactly ONE MFMA). Fix: each wave now owns
// 32 q-rows (2 m-tiles), so every K/V B-fragment read is reused by 2 MFMAs.
// Block = 4 waves x 32 rows = 128 q-rows. ds-cy per MFMA halves -> expect
// MfmaUtil ~32% -> ~50%.
// Everything else identical to the verified round-0 kernel: single-buffer
// XOR-swizzled DMA staging, 2 barriers/iter, no-max softmax (exp2 domain,
// shift-invariant), P transposed C->A layout through per-wave padded LDS.
// Causality: a wave whose rows all precede the tile skips compute (uniform
// branch) but keeps barriers. Diagonal mask only on the tile containing the
// wave's diagonal.
// ---------------------------------------------------------------------------
__global__ void __launch_bounds__(256)
attn_kernel(const __hip_bfloat16* __restrict__ Qbuf,
            const __hip_bfloat16* __restrict__ Kbuf,
            const __hip_bfloat16* __restrict__ Vtbuf,
            __hip_bfloat16* __restrict__ Obuf)
{
  __shared__ __align__(16) short KtS[64*128];      // 16 KB: [key][d], 16 ch/row
  __shared__ __align__(16) short VtS[128*64];      // 16 KB: [d][key], 8 ch/row
  __shared__ __align__(16) short PtS[4][2][16*72]; // 18 KB: per-wave per-mt P

  const int qb   = blockIdx.x * 128;
  const int bh   = blockIdx.y;               // b*NHEADS + h
  const int b    = bh >> 5, h = bh & 31;
  const int g    = h >> 2;                   // rep = 4
  const int tid  = threadIdx.x;
  const int wave = tid >> 6, lane = tid & 63;
  const int quad = lane >> 4, l15 = lane & 15;
  const int qw   = qb + wave*32;             // this wave's 32 q rows

  const __hip_bfloat16* Qp = Qbuf  + ((size_t)bh*S_LEN + qw) * HEADD;
  const __hip_bfloat16* Kp = Kbuf  + ((size_t)(b*NGROUPS + g)*S_LEN) * HEADD;
  const __hip_bfloat16* Vp = Vtbuf + ((size_t)(b*NGROUPS + g)*HEADD) * S_LEN;

  // Q fragments, 2 m-tiles (already scaled by 1/sqrt(d)*log2e in rope_kernel)
  short8 aq[2][4];
  #pragma unroll
  for (int mt = 0; mt < 2; ++mt)
    #pragma unroll
    for (int dc = 0; dc < 4; ++dc)
      aq[mt][dc] = *(const short8*)&Qp[(size_t)(mt*16 + l15)*HEADD + dc*32 + quad*8];

  floatx4 O[2][8] = {};
  float li[2][4] = {};                   // per-lane partial row sums

  const int ktend = qb + 128;
  for (int kt = 0; kt < ktend; kt += 64) {
    // ---- stage K (64x128) and V^T (128x64) tiles, XOR-swizzled ----
    #pragma unroll
    for (int i = 0; i < 4; ++i) {
      const int cb  = (i*4 + wave) * 64;   // wave-uniform chunk base
      const int idx = cb + lane;
      { // K: 16 chunks per key row; chunk (r,cl) holds global chunk cl^(r&15)
        const int r = idx >> 4, cl = idx & 15;
        const int gc = cl ^ (r & 15);
        async_ld16(Kp + (size_t)(kt + r)*HEADD + gc*8, KtS + cb*8);
      }
      { // V: 8 chunks per d row; chunk (r,cl) holds global chunk cl^(r&7)
        const int r = idx >> 3, cl = idx & 7;
        const int gc = cl ^ (r & 7);
        async_ld16(Vp + (size_t)r*S_LEN + kt + gc*8, VtS + cb*8);
      }
    }
    __syncthreads();   // barrier drains vmcnt(0): tiles ready

    if (kt < qw + 32) {     // wave-uniform: any of this wave's rows see tile
      // ---- S = Q K^T : 2 m-tiles x 64 keys; each bk read feeds 2 MFMAs ----
      floatx4 s[2][4] = {};
      __builtin_amdgcn_s_setprio(1);
      #pragma unroll
      for (int dc = 0; dc < 4; ++dc) {
        #pragma unroll
        for (int kc = 0; kc < 4; ++kc) {
          const int row = kc*16 + l15;
          const int ch  = (dc*4 + quad) ^ l15;
          const short8 bk = *(const short8*)&KtS[row*128 + ch*8];
          #pragma unroll
          for (int mt = 0; mt < 2; ++mt)
            s[mt][kc] = __builtin_amdgcn_mfma_f32_16x16x32_bf16(
                aq[mt][dc], bk, s[mt][kc], 0, 0, 0);
        }
      }
      __builtin_amdgcn_s_setprio(0);

      // ---- no-max softmax + P transpose, per m-tile ----
      short8 pa[2][2];
      #pragma unroll
      for (int mt = 0; mt < 2; ++mt) {
        const int rowbase = qw + mt*16;
        if (kt + 64 > rowbase) {         // tile straddles this m-tile's diagonal
          #pragma unroll
          for (int r = 0; r < 4; ++r) {
            const int row = rowbase + quad*4 + r;
            float rs = 0.f;
            #pragma unroll
            for (int kc = 0; kc < 4; ++kc) {
              const int col = kt + kc*16 + l15;
              const float p = (col > row) ? 0.0f : __builtin_amdgcn_exp2f(s[mt][kc][r]);
              s[mt][kc][r] = p; rs += p;
            }
            li[mt][r] += rs;
          }
        } else {
          #pragma unroll
          for (int r = 0; r < 4; ++r) {
            float rs = 0.f;
            #pragma unroll
            for (int kc = 0; kc < 4; ++kc) {
              const float p = __builtin_amdgcn_exp2f(s[mt][kc][r]);
              s[mt][kc][r] = p; rs += p;
            }
            li[mt][r] += rs;
          }
        }
        // C-layout -> A-layout via wave-private padded LDS tile
        #pragma unroll
        for (int r = 0; r < 4; ++r)
          #pragma unroll
          for (int kc = 0; kc < 4; ++kc)
            PtS[wave][mt][(quad*4 + r)*72 + kc*16 + l15] = (short)f2bf_bits(s[mt][kc][r]);
        // same-wave RAW through LDS: ordered by lgkmcnt
        pa[mt][0] = *(const short8*)&PtS[wave][mt][l15*72 +      quad*8];
        pa[mt][1] = *(const short8*)&PtS[wave][mt][l15*72 + 32 + quad*8];
      }

      // ---- O += P V : each bv read feeds 2 MFMAs ----
      __builtin_amdgcn_s_setprio(1);
      #pragma unroll
      for (int dt = 0; dt < 8; ++dt) {
        const int row = dt*16 + l15;
        const int c0 = quad ^ (l15 & 7);
        const int c1 = (4 + quad) ^ (l15 & 7);
        const short8 bv0 = *(const short8*)&VtS[row*64 + c0*8];
        const short8 bv1 = *(const short8*)&VtS[row*64 + c1*8];
        #pragma unroll
        for (int mt = 0; mt < 2; ++mt) {
          O[mt][dt] = __builtin_amdgcn_mfma_f32_16x16x32_bf16(pa[mt][0], bv0, O[mt][dt], 0, 0, 0);
          O[mt][dt] = __builtin_amdgcn_mfma_f32_16x16x32_bf16(pa[mt][1], bv1, O[mt][dt], 0, 0, 0);
        }
      }
      __builtin_amdgcn_s_setprio(0);
    }

    __syncthreads();   // all tile reads done before next stage overwrites
  }

  // ---- epilogue: reduce l across the 16 col-lanes, scale, write ----
  #pragma unroll
  for (int mt = 0; mt < 2; ++mt) {
    float inv[4];
    #pragma unroll
    for (int r = 0; r < 4; ++r) {
      float l = li[mt][r];
      l += __shfl_xor(l, 1, 16);
      l += __shfl_xor(l, 2, 16);
      l += __shfl_xor(l, 4, 16);
      l += __shfl_xor(l, 8, 16);
      inv[r] = 1.0f / l;
    }
    #pragma unroll
    for (int dt = 0; dt < 8; ++dt)
      #pragma unroll
      for (int r = 0; r < 4; ++r) {
        const int row = qw + mt*16 + quad*4 + r;
        Obuf[((size_t)row*BATCH + b)*HDIM + h*HEADD + dt*16 + l15] =
            __float2bfloat16(O[mt][dt][r] * inv[r]);
      }
  }
}

// ---------------------------------------------------------------------------
extern "C" void kernel_launch(void* const* d_in, const int* in_sizes, int n_in,
                              void* d_out, int out_size, void* d_ws, size_t ws_size,
                              hipStream_t stream)
{
  const float* x    = (const float*)d_in[0];
  const float* rope = (const float*)d_in[1];
  const float* Wqkv = (const float*)d_in[2];
  const float* bqkv = (const float*)d_in[3];
  const float* Wd   = (const float*)d_in[4];
  float* out = (float*)d_out;

  const size_t MiB = 1024*1024;
  char* ws = (char*)d_ws;
  __hip_bfloat16* xb    = (__hip_bfloat16*)(ws);              // 32 MiB
  __hip_bfloat16* Wqkvb = (__hip_bfloat16*)(ws + 32*MiB);     // 48 MiB
  __hip_bfloat16* Wdb   = (__hip_bfloat16*)(ws + 80*MiB);     // 32 MiB
  __hip_bfloat16* Qbuf  = (__hip_bfloat16*)(ws + 112*MiB);    // 32 MiB
  __hip_bfloat16* Kbuf  = (__hip_bfloat16*)(ws + 144*MiB);    //  8 MiB
  __hip_bfloat16* Vt    = (__hip_bfloat16*)(ws + 152*MiB);    //  8 MiB
  __hip_bfloat16* Ob    = (__hip_bfloat16*)(ws + 160*MiB);    // 32 MiB

  // 0) f32 -> bf16 conversions
  {
    const int nx = S_LEN*BATCH*HDIM/4;
    const int nq = QKV_N*HDIM/4;
    const int nd = HDIM*HDIM/4;
    cvt_f32_bf16<<<(nx+255)/256, 256, 0, stream>>>((const float4*)x,    (ushort4*)xb,    nx);
    cvt_f32_bf16<<<(nq+255)/256, 256, 0, stream>>>((const float4*)Wqkv, (ushort4*)Wqkvb, nq);
    cvt_f32_bf16<<<(nd+255)/256, 256, 0, stream>>>((const float4*)Wd,   (ushort4*)Wdb,   nd);
  }

  // 1) QKV projection + scatter (M=4096, N=6144, K=4096)
  dim3 g1(QKV_N/128, (S_LEN*BATCH)/128);
  gemm128<1><<<g1, 256, 0, stream>>>(xb, Wqkvb, bqkv, nullptr,
                                     Qbuf, Kbuf, Vt,
                                     S_LEN*BATCH, QKV_N, HDIM);

  // 2) RoPE in-place on Q (+softmax prescale) and K
  const int total_pairs = BATCH*(NHEADS+NGROUPS)*S_LEN*64;
  rope_kernel<<<total_pairs/256, 256, 0, stream>>>(Qbuf, Kbuf, rope);

  // 3) causal flash attention (128 q-rows per block, 4 waves x 32 rows)
  dim3 ga(S_LEN/128, BATCH*NHEADS);
  attn_kernel<<<ga, 256, 0, stream>>>(Qbuf, Kbuf, Vt, Ob);

  // 4) dense projection (M=4096, N=4096, K=4096), f32 out
  dim3 g2(HDIM/128, (S_LEN*BATCH)/128);
  gemm128<0><<<g2, 256, 0, stream>>>(Ob, Wdb, nullptr, out,
                                     nullptr, nullptr, nullptr,
                                     S_LEN*BATCH, HDIM, HDIM);
}